// Round 8
// baseline (431.079 us; speedup 1.0000x reference)
//
#include <hip/hip_runtime.h>
#include <hip/hip_bf16.h>
#include <type_traits>

typedef unsigned short u16;
typedef __attribute__((ext_vector_type(8))) short bf16x8;
typedef __attribute__((ext_vector_type(4))) short bf16x4;
typedef __attribute__((ext_vector_type(4))) float f32x4;

#define B_  4
#define T_  2048
#define C_  1024
#define H_  16
#define DH_ 64
#define M_  (B_*T_)   // 8192

// async global->LDS, 16B per lane; LDS dest = wave-uniform base + lane*16
#define GLDS16(g, l) __builtin_amdgcn_global_load_lds( \
    (const __attribute__((address_space(1))) void*)(g), \
    (__attribute__((address_space(3))) void*)(l), 16, 0, 0)

__device__ __forceinline__ u16 f2b(float f) {
  union { __hip_bfloat16 h; u16 u; } cv;
  cv.h = __float2bfloat16(f);
  return cv.u;
}

// 16x16x16 bf16 MFMA (2-VGPR A/B): A[m=l15][k=quad*4+j], B[k=quad*4+j][n=l15],
// C/D standard 16x16 layout. B-operand layout == C-layout -> P^T feeds PV directly.
#if defined(__has_builtin)
#if __has_builtin(__builtin_amdgcn_mfma_f32_16x16x16bf16_1k)
#define HAVE_MFMA16 1
#endif
#endif
__device__ __forceinline__ f32x4 mfma16(bf16x4 a, bf16x4 b, f32x4 c) {
#ifdef HAVE_MFMA16
  return __builtin_amdgcn_mfma_f32_16x16x16bf16_1k(a, b, c, 0, 0, 0);
#else
  f32x4 d;
  asm volatile("v_mfma_f32_16x16x16_bf16 %0, %1, %2, %3\n\ts_nop 7"
               : "=v"(d) : "v"(a), "v"(b), "v"(c));
  return d;
#endif
}

// ---------------- all fp32 -> bf16 casts in one launch ----------------
__global__ void cast_all_kernel(const float* __restrict__ x,  const float* __restrict__ w0,
                                const float* __restrict__ w1, const float* __restrict__ w2,
                                u16* __restrict__ xo, u16* __restrict__ o0,
                                u16* __restrict__ o1, u16* __restrict__ o2) {
  int bid = blockIdx.x;
  const float* src; u16* dst; int blk;
  if (bid < 8192) { src = x; dst = xo; blk = bid; }
  else {
    int k = bid - 8192, w = k >> 10;
    src = (w == 0) ? w0 : (w == 1) ? w1 : w2;
    dst = (w == 0) ? o0 : (w == 1) ? o1 : o2;
    blk = k & 1023;
  }
  int i = (blk * 256 + threadIdx.x) * 4;
  float4 v = *(const float4*)(src + i);
  unsigned lo = (unsigned)f2b(v.x) | ((unsigned)f2b(v.y) << 16);
  unsigned hi = (unsigned)f2b(v.z) | ((unsigned)f2b(v.w) << 16);
  uint2 p; p.x = lo; p.y = hi;
  *(uint2*)(dst + i) = p;
}

// ---------------- GEMM (4-wave): C[m,n] = sum_k A[m,k]*B[n,k], 128x128, BK=64 ----------------
__global__ __launch_bounds__(256) void gemm_bt_kernel(
    const u16* __restrict__ A, const u16* __restrict__ Bm,
    void* __restrict__ Cout, int mode)
{
  constexpr int K = 1024;
  __shared__ __align__(16) u16 As[128 * 64];
  __shared__ __align__(16) u16 Bs[128 * 64];

  const int tid  = threadIdx.x;
  const int wave = tid >> 6, lane = tid & 63;
  const int quad = lane >> 4, l15 = lane & 15;
  const int x7   = l15 & 7;
  const int wm = (wave >> 1) * 64, wn = (wave & 1) * 64;
  const int tm = blockIdx.x * 128, tn = blockIdx.y * 128;

  f32x4 acc[4][4] = {};

  for (int k0 = 0; k0 < K; k0 += 64) {
#pragma unroll
    for (int it = 0; it < 4; it++) {
      int ch  = it * 256 + tid;
      int row = ch >> 3;
      int cc  = (ch & 7) ^ (row & 7);
      GLDS16(A  + (size_t)(tm + row) * K + k0 + cc * 8, &As[(it * 256 + wave * 64) * 8]);
      GLDS16(Bm + (size_t)(tn + row) * K + k0 + cc * 8, &Bs[(it * 256 + wave * 64) * 8]);
    }
    __syncthreads();

#pragma unroll
    for (int ks = 0; ks < 2; ks++) {
      bf16x8 af[4], bfr[4];
#pragma unroll
      for (int t = 0; t < 4; t++) {
        int co = ((ks * 4 + quad) ^ x7) * 8;
        af[t]  = *(const bf16x8*)(&As[(wm + t * 16 + l15) * 64 + co]);
        bfr[t] = *(const bf16x8*)(&Bs[(wn + t * 16 + l15) * 64 + co]);
      }
#pragma unroll
      for (int mt = 0; mt < 4; mt++)
#pragma unroll
        for (int nt = 0; nt < 4; nt++)
          acc[mt][nt] = __builtin_amdgcn_mfma_f32_16x16x32_bf16(af[mt], bfr[nt], acc[mt][nt], 0, 0, 0);
    }
    __syncthreads();
  }

  if (mode == 0) {
    u16* out = (u16*)Cout;
    if (tn < 1024) {
#pragma unroll
      for (int mt = 0; mt < 4; mt++)
#pragma unroll
        for (int nt = 0; nt < 4; nt++)
#pragma unroll
          for (int r = 0; r < 4; r++) {
            int gm = tm + wm + mt * 16 + quad * 4 + r;
            int gn = tn + wn + nt * 16 + l15;
            int b = gm >> 11, t = gm & 2047;
            int h = gn >> 6, d = gn & 63;
            out[((size_t)((b * 16 + h) * 2048 + t) << 6) + d] = f2b(acc[mt][nt][r]);
          }
    } else {
      // V half -> Vt [B,H,Dh,T] (fused transpose)
#pragma unroll
      for (int mt = 0; mt < 4; mt++)
#pragma unroll
        for (int nt = 0; nt < 4; nt++) {
          int gm0 = tm + wm + mt * 16 + quad * 4;
          int gn  = tn - 1024 + wn + nt * 16 + l15;
          int b = gm0 >> 11, t0 = gm0 & 2047;
          int h = gn >> 6, d = gn & 63;
          alignas(8) u16 tmp[4];
#pragma unroll
          for (int r = 0; r < 4; r++) tmp[r] = f2b(acc[mt][nt][r]);
          *(ushort4*)(out + 8388608 + (((size_t)(b * 16 + h) * 64 + d) << 11) + t0)
              = *(const ushort4*)tmp;
        }
    }
  } else {
    float* out = (float*)Cout;
#pragma unroll
    for (int mt = 0; mt < 4; mt++)
#pragma unroll
      for (int nt = 0; nt < 4; nt++)
#pragma unroll
        for (int r = 0; r < 4; r++) {
          int gm = tm + wm + mt * 16 + quad * 4 + r;
          int gn = tn + wn + nt * 16 + l15;
          out[(size_t)gm * 1024 + gn] = acc[mt][nt][r];
        }
  }
}

// ---------------- GEMM (8-wave, fp32 out): 128x128 tile, 512 threads ----------------
__global__ __launch_bounds__(512, 4) void gemm_bt512_kernel(
    const u16* __restrict__ A, const u16* __restrict__ Bm, float* __restrict__ out)
{
  constexpr int K = 1024;
  __shared__ __align__(16) u16 As[128 * 64];
  __shared__ __align__(16) u16 Bs[128 * 64];

  const int tid  = threadIdx.x;
  const int wave = tid >> 6, lane = tid & 63;   // wave 0..7
  const int quad = lane >> 4, l15 = lane & 15;
  const int x7   = l15 & 7;
  const int wm = (wave >> 1) * 32, wn = (wave & 1) * 64;
  const int tm = blockIdx.x * 128, tn = blockIdx.y * 128;

  f32x4 acc[2][4] = {};

  for (int k0 = 0; k0 < K; k0 += 64) {
#pragma unroll
    for (int it = 0; it < 2; it++) {
      int ch  = it * 512 + tid;
      int row = ch >> 3;
      int cc  = (ch & 7) ^ (row & 7);
      GLDS16(A  + (size_t)(tm + row) * K + k0 + cc * 8, &As[(it * 512 + wave * 64) * 8]);
      GLDS16(Bm + (size_t)(tn + row) * K + k0 + cc * 8, &Bs[(it * 512 + wave * 64) * 8]);
    }
    __syncthreads();

#pragma unroll
    for (int ks = 0; ks < 2; ks++) {
      bf16x8 af[2], bfr[4];
      int co = ((ks * 4 + quad) ^ x7) * 8;
#pragma unroll
      for (int t = 0; t < 2; t++)
        af[t]  = *(const bf16x8*)(&As[(wm + t * 16 + l15) * 64 + co]);
#pragma unroll
      for (int t = 0; t < 4; t++)
        bfr[t] = *(const bf16x8*)(&Bs[(wn + t * 16 + l15) * 64 + co]);
#pragma unroll
      for (int mt = 0; mt < 2; mt++)
#pragma unroll
        for (int nt = 0; nt < 4; nt++)
          acc[mt][nt] = __builtin_amdgcn_mfma_f32_16x16x32_bf16(af[mt], bfr[nt], acc[mt][nt], 0, 0, 0);
    }
    __syncthreads();
  }

#pragma unroll
  for (int mt = 0; mt < 2; mt++)
#pragma unroll
    for (int nt = 0; nt < 4; nt++)
#pragma unroll
      for (int r = 0; r < 4; r++) {
        int gm = tm + wm + mt * 16 + quad * 4 + r;
        int gn = tn + wn + nt * 16 + l15;
        out[(size_t)gm * 1024 + gn] = acc[mt][nt][r];
      }
}

// ---------------- causal flash attention, K==Q (reference bug), bf16 MFMA ----------------
// No-P-round-trip design: S^T = K Q^T (x32 MFMA, args swapped) puts P^T in C-layout,
// which IS the 16x16x16 B-operand layout -> PV as O^T = V^T P^T via mfma16, in-lane pack
// only. LDS = K+Vt tiles (16KB). 2048 two-wave blocks (64 q-rows); per-CU resident set
// (bid = c+256n) gets q-tiles i=(7-j)*4+((t+j)&3) -> every CU sums 132 tile-units, LPT
// order, same bh per CU (XCD-packed L2). Fixed-max softmax, lsum via ones-MFMA.
__global__ __launch_bounds__(128, 4) void attn_kernel(
    const u16* __restrict__ Q, const u16* __restrict__ Vt, u16* __restrict__ AO)
{
  __shared__ __align__(16) u16 Ks[4096];        // [key 64][dh 64] swizzled, 8KB
  __shared__ __align__(16) u16 Vs[4096];        // [d 64][key 64] swizzled, 8KB

  const int tid  = threadIdx.x;
  const int wave = tid >> 6, lane = tid & 63;
  const int quad = lane >> 4, l15 = lane & 15;
  const int x7   = l15 & 7;
  const int bid  = blockIdx.x;
  // bits 0-5: bh, XCD-packed (bid%8 -> XCD; each XCD owns 8 bh = 4MB K+V = its L2)
  const int bh = (bid & 7) * 8 + ((bid >> 3) & 7);
  const int m  = bid >> 6;                       // 0..31
  const int jj = m >> 2, tt = m & 3;
  const int i  = (7 - jj) * 4 + ((tt + jj) & 3); // balanced-LPT q-tile (64 rows)
  const int b = bh >> 4, h = bh & 15;
  const u16* Qbh = Q  + (size_t)bh * (T_ * DH_);
  const u16* Vbh = Vt + (size_t)bh * (DH_ * T_);
  const int q0w = i * 64 + wave * 32;      // wave's first q-row
  const int nkb = i + 1;                   // k-tiles (64 keys); both waves share diag tile

  const float C1 = 0.18033688f;    // log2(e)/sqrt(64)
  const float C2 = -28.8539008f;   // -20*log2(e)  (fixed max M=20, shift-invariant)
  const bf16x4 ones4 = { 0x3F80, 0x3F80, 0x3F80, 0x3F80 };

  // Q fragments (B-operand of S^T: n=q=l15, k=dh=quad*8+j), direct global, once
  bf16x8 qf[2][2];
#pragma unroll
  for (int mt = 0; mt < 2; mt++)
#pragma unroll
    for (int ks = 0; ks < 2; ks++)
      qf[mt][ks] = *(const bf16x8*)(Qbh + (size_t)(q0w + mt * 16 + l15) * DH_ + ks * 32 + quad * 8);

  f32x4 o[2][4] = {};      // O^T[d][q]: [mt(q)][dt(d)], C-layout row=d_local, col=q_local
  f32x4 lsumv[2] = {};

  auto tilecomp = [&](int kb, auto DIAGC) {
    constexpr bool DIAG = decltype(DIAGC)::value;
    const int k0 = kb * 64;
    // S^T = K Q^T: A=kf (m=key), B=qf (n=q); C-layout row=key_local=quad*4+r, col=q=l15
    f32x4 st[4][2] = {};
#pragma unroll
    for (int ks = 0; ks < 2; ks++)
#pragma unroll
      for (int nt = 0; nt < 4; nt++) {
        bf16x8 kf = *(const bf16x8*)(&Ks[(nt * 16 + l15) * 64 + (((ks * 4 + quad) ^ x7) * 8)]);
#pragma unroll
        for (int mt = 0; mt < 2; mt++)
          st[nt][mt] = __builtin_amdgcn_mfma_f32_16x16x32_bf16(kf, qf[mt][ks], st[nt][mt], 0, 0, 0);
      }

    // softmax + in-lane pack to P^T 16x16x16-B-fragments (k=quad*4+r ascending)
    bf16x4 pt[4][2];
#pragma unroll
    for (int nt = 0; nt < 4; nt++)
#pragma unroll
      for (int mt = 0; mt < 2; mt++)
#pragma unroll
        for (int r = 0; r < 4; r++) {
          float p = __builtin_amdgcn_exp2f(st[nt][mt][r] * C1 + C2);
          if constexpr (DIAG) {
            int kg = k0 + nt * 16 + quad * 4 + r;
            int qg = q0w + mt * 16 + l15;
            p = (kg <= qg) ? p : 0.0f;
          }
          pt[nt][mt][r] = (short)f2b(p);
        }

    // O^T += V^T P^T (mfma16: A=Vt frag, B=pt); lsum cols via ones-MFMA
#pragma unroll
    for (int kc = 0; kc < 4; kc++) {           // 16-key chunks
#pragma unroll
      for (int mt = 0; mt < 2; mt++)
        lsumv[mt] = mfma16(ones4, pt[kc][mt], lsumv[mt]);
#pragma unroll
      for (int dt = 0; dt < 4; dt++) {
        // Vt frag: A[m=d=l15][k=key=quad*4+j]; swizzled b64 read
        bf16x4 vf = *(const bf16x4*)(&Vs[(dt * 16 + l15) * 64
                        + (((kc * 2 + (quad >> 1)) ^ x7) * 8) + (quad & 1) * 4]);
#pragma unroll
        for (int mt = 0; mt < 2; mt++)
          o[mt][dt] = mfma16(vf, pt[kc][mt], o[mt][dt]);
      }
    }
  };

  for (int kb = 0; kb < nkb; kb++) {
    const int k0 = kb * 64;
    // stage K-tile [key][dh] and Vt-tile [d][key]: 512 chunks each, 4/thread, swizzled
#pragma unroll
    for (int it = 0; it < 4; it++) {
      int ch  = it * 128 + tid;
      int row = ch >> 3;
      int cc  = (ch & 7) ^ (row & 7);
      GLDS16(Qbh + (size_t)(k0 + row) * DH_ + cc * 8, &Ks[(it * 128 + wave * 64) * 8]);
      GLDS16(Vbh + (size_t)row * T_ + k0 + cc * 8,    &Vs[(it * 128 + wave * 64) * 8]);
    }
    __syncthreads();

    if (kb < nkb - 1) tilecomp(kb, std::false_type{});
    else              tilecomp(kb, std::true_type{});
    __syncthreads();
  }

  // epilogue: rl = 1/colsum; store O^T -> AO[b][t][h*64+d], 4 d-contig per ushort4
#pragma unroll
  for (int mt = 0; mt < 2; mt++) {
    float rl = 1.0f / lsumv[mt][0];
    int t = q0w + mt * 16 + l15;
#pragma unroll
    for (int dt = 0; dt < 4; dt++) {
      alignas(8) u16 tmp[4];
#pragma unroll
      for (int r = 0; r < 4; r++) tmp[r] = f2b(o[mt][dt][r] * rl);
      *(ushort4*)(AO + ((size_t)(b * T_ + t)) * C_ + h * DH_ + dt * 16 + quad * 4)
          = *(const ushort4*)tmp;
    }
  }
}

extern "C" void kernel_launch(void* const* d_in, const int* in_sizes, int n_in,
                              void* d_out, int out_size, void* d_ws, size_t ws_size,
                              hipStream_t stream) {
  (void)in_sizes; (void)n_in; (void)out_size; (void)ws_size;
  const float* x  = (const float*)d_in[0];
  const float* Wq = (const float*)d_in[1];
  // d_in[2] = W_k unused (reference bug: K uses W_q)
  const float* Wv = (const float*)d_in[3];
  const float* Wo = (const float*)d_in[4];

  // workspace (u16 elems); AO reuses Xb slot (dead after gemm1)
  u16* Xb  = (u16*)d_ws;            // 8388608 : x bf16; later AO [B,T,C]
  u16* AOw = Xb;
  u16* Wqb = Xb  + 8388608;         // 1048576
  u16* Wvb = Wqb + 1048576;         // 1048576 (adjacent -> fused N=2048 GEMM)
  u16* Wob = Wvb + 1048576;         // 1048576
  u16* Qw  = Wob + 1048576;         // 8388608 : Q [B,H,T,Dh]
  u16* Vtw = Qw  + 8388608;         // 8388608 : Vt [B,H,Dh,T] (gemm1 writes directly)
  // total 54,525,952 bytes

  cast_all_kernel<<<11264, 256, 0, stream>>>(x, Wq, Wv, Wo, Xb, Wqb, Wvb, Wob);

  // fused Q+V projection; V half written pre-transposed (Vt base = Qw + 8388608)
  gemm_bt_kernel<<<dim3(64, 16), 256, 0, stream>>>(Xb, Wqb, (void*)Qw, 0);

  attn_kernel<<<2048, 128, 0, stream>>>(Qw, Vtw, AOw);

  gemm_bt512_kernel<<<dim3(64, 8), 512, 0, stream>>>(AOw, Wob, (float*)d_out);
}

// Round 9
// 282.669 us; speedup vs baseline: 1.5250x; 1.5250x over previous
//
#include <hip/hip_runtime.h>
#include <hip/hip_bf16.h>
#include <type_traits>

typedef unsigned short u16;
typedef __attribute__((ext_vector_type(8))) short bf16x8;
typedef __attribute__((ext_vector_type(4))) float f32x4;

#define B_  4
#define T_  2048
#define C_  1024
#define H_  16
#define DH_ 64
#define M_  (B_*T_)   // 8192

// async global->LDS, 16B per lane; LDS dest = wave-uniform base + lane*16
#define GLDS16(g, l) __builtin_amdgcn_global_load_lds( \
    (const __attribute__((address_space(1))) void*)(g), \
    (__attribute__((address_space(3))) void*)(l), 16, 0, 0)

__device__ __forceinline__ u16 f2b(float f) {
  union { __hip_bfloat16 h; u16 u; } cv;
  cv.h = __float2bfloat16(f);
  return cv.u;
}

// ---------------- all fp32 -> bf16 casts in one launch ----------------
__global__ void cast_all_kernel(const float* __restrict__ x,  const float* __restrict__ w0,
                                const float* __restrict__ w1, const float* __restrict__ w2,
                                u16* __restrict__ xo, u16* __restrict__ o0,
                                u16* __restrict__ o1, u16* __restrict__ o2) {
  int bid = blockIdx.x;
  const float* src; u16* dst; int blk;
  if (bid < 8192) { src = x; dst = xo; blk = bid; }
  else {
    int k = bid - 8192, w = k >> 10;
    src = (w == 0) ? w0 : (w == 1) ? w1 : w2;
    dst = (w == 0) ? o0 : (w == 1) ? o1 : o2;
    blk = k & 1023;
  }
  int i = (blk * 256 + threadIdx.x) * 4;
  float4 v = *(const float4*)(src + i);
  unsigned lo = (unsigned)f2b(v.x) | ((unsigned)f2b(v.y) << 16);
  unsigned hi = (unsigned)f2b(v.z) | ((unsigned)f2b(v.w) << 16);
  uint2 p; p.x = lo; p.y = hi;
  *(uint2*)(dst + i) = p;
}

// ---------------- GEMM (4-wave): C[m,n] = sum_k A[m,k]*B[n,k], 128x128, BK=64 ----------------
__global__ __launch_bounds__(256) void gemm_bt_kernel(
    const u16* __restrict__ A, const u16* __restrict__ Bm,
    void* __restrict__ Cout, int mode)
{
  constexpr int K = 1024;
  __shared__ __align__(16) u16 As[128 * 64];
  __shared__ __align__(16) u16 Bs[128 * 64];

  const int tid  = threadIdx.x;
  const int wave = tid >> 6, lane = tid & 63;
  const int quad = lane >> 4, l15 = lane & 15;
  const int x7   = l15 & 7;
  const int wm = (wave >> 1) * 64, wn = (wave & 1) * 64;
  const int tm = blockIdx.x * 128, tn = blockIdx.y * 128;

  f32x4 acc[4][4] = {};

  for (int k0 = 0; k0 < K; k0 += 64) {
#pragma unroll
    for (int it = 0; it < 4; it++) {
      int ch  = it * 256 + tid;
      int row = ch >> 3;
      int cc  = (ch & 7) ^ (row & 7);
      GLDS16(A  + (size_t)(tm + row) * K + k0 + cc * 8, &As[(it * 256 + wave * 64) * 8]);
      GLDS16(Bm + (size_t)(tn + row) * K + k0 + cc * 8, &Bs[(it * 256 + wave * 64) * 8]);
    }
    __syncthreads();

#pragma unroll
    for (int ks = 0; ks < 2; ks++) {
      bf16x8 af[4], bfr[4];
#pragma unroll
      for (int t = 0; t < 4; t++) {
        int co = ((ks * 4 + quad) ^ x7) * 8;
        af[t]  = *(const bf16x8*)(&As[(wm + t * 16 + l15) * 64 + co]);
        bfr[t] = *(const bf16x8*)(&Bs[(wn + t * 16 + l15) * 64 + co]);
      }
#pragma unroll
      for (int mt = 0; mt < 4; mt++)
#pragma unroll
        for (int nt = 0; nt < 4; nt++)
          acc[mt][nt] = __builtin_amdgcn_mfma_f32_16x16x32_bf16(af[mt], bfr[nt], acc[mt][nt], 0, 0, 0);
    }
    __syncthreads();
  }

  if (mode == 0) {
    u16* out = (u16*)Cout;
    if (tn < 1024) {
#pragma unroll
      for (int mt = 0; mt < 4; mt++)
#pragma unroll
        for (int nt = 0; nt < 4; nt++)
#pragma unroll
          for (int r = 0; r < 4; r++) {
            int gm = tm + wm + mt * 16 + quad * 4 + r;
            int gn = tn + wn + nt * 16 + l15;
            int b = gm >> 11, t = gm & 2047;
            int h = gn >> 6, d = gn & 63;
            out[((size_t)((b * 16 + h) * 2048 + t) << 6) + d] = f2b(acc[mt][nt][r]);
          }
    } else {
      // V half -> Vt [B,H,Dh,T] (fused transpose)
#pragma unroll
      for (int mt = 0; mt < 4; mt++)
#pragma unroll
        for (int nt = 0; nt < 4; nt++) {
          int gm0 = tm + wm + mt * 16 + quad * 4;
          int gn  = tn - 1024 + wn + nt * 16 + l15;
          int b = gm0 >> 11, t0 = gm0 & 2047;
          int h = gn >> 6, d = gn & 63;
          alignas(8) u16 tmp[4];
#pragma unroll
          for (int r = 0; r < 4; r++) tmp[r] = f2b(acc[mt][nt][r]);
          *(ushort4*)(out + 8388608 + (((size_t)(b * 16 + h) * 64 + d) << 11) + t0)
              = *(const ushort4*)tmp;
        }
    }
  } else {
    float* out = (float*)Cout;
#pragma unroll
    for (int mt = 0; mt < 4; mt++)
#pragma unroll
      for (int nt = 0; nt < 4; nt++)
#pragma unroll
        for (int r = 0; r < 4; r++) {
          int gm = tm + wm + mt * 16 + quad * 4 + r;
          int gn = tn + wn + nt * 16 + l15;
          out[(size_t)gm * 1024 + gn] = acc[mt][nt][r];
        }
  }
}

// ---------------- GEMM (8-wave, fp32 out): 128x128 tile, 512 threads ----------------
__global__ __launch_bounds__(512, 4) void gemm_bt512_kernel(
    const u16* __restrict__ A, const u16* __restrict__ Bm, float* __restrict__ out)
{
  constexpr int K = 1024;
  __shared__ __align__(16) u16 As[128 * 64];
  __shared__ __align__(16) u16 Bs[128 * 64];

  const int tid  = threadIdx.x;
  const int wave = tid >> 6, lane = tid & 63;   // wave 0..7
  const int quad = lane >> 4, l15 = lane & 15;
  const int x7   = l15 & 7;
  const int wm = (wave >> 1) * 32, wn = (wave & 1) * 64;
  const int tm = blockIdx.x * 128, tn = blockIdx.y * 128;

  f32x4 acc[2][4] = {};

  for (int k0 = 0; k0 < K; k0 += 64) {
#pragma unroll
    for (int it = 0; it < 2; it++) {
      int ch  = it * 512 + tid;
      int row = ch >> 3;
      int cc  = (ch & 7) ^ (row & 7);
      GLDS16(A  + (size_t)(tm + row) * K + k0 + cc * 8, &As[(it * 512 + wave * 64) * 8]);
      GLDS16(Bm + (size_t)(tn + row) * K + k0 + cc * 8, &Bs[(it * 512 + wave * 64) * 8]);
    }
    __syncthreads();

#pragma unroll
    for (int ks = 0; ks < 2; ks++) {
      bf16x8 af[2], bfr[4];
      int co = ((ks * 4 + quad) ^ x7) * 8;
#pragma unroll
      for (int t = 0; t < 2; t++)
        af[t]  = *(const bf16x8*)(&As[(wm + t * 16 + l15) * 64 + co]);
#pragma unroll
      for (int t = 0; t < 4; t++)
        bfr[t] = *(const bf16x8*)(&Bs[(wn + t * 16 + l15) * 64 + co]);
#pragma unroll
      for (int mt = 0; mt < 2; mt++)
#pragma unroll
        for (int nt = 0; nt < 4; nt++)
          acc[mt][nt] = __builtin_amdgcn_mfma_f32_16x16x32_bf16(af[mt], bfr[nt], acc[mt][nt], 0, 0, 0);
    }
    __syncthreads();
  }

#pragma unroll
  for (int mt = 0; mt < 2; mt++)
#pragma unroll
    for (int nt = 0; nt < 4; nt++)
#pragma unroll
      for (int r = 0; r < 4; r++) {
        int gm = tm + wm + mt * 16 + quad * 4 + r;
        int gn = tn + wn + nt * 16 + l15;
        out[(size_t)gm * 1024 + gn] = acc[mt][nt][r];
      }
}

// ---------------- causal flash attention, K==Q (reference bug), bf16 MFMA ----------------
// R7 datapath, finer decomposition: 2048 four-wave blocks, 64 q-rows/block, 16 rows/wave.
// LDS 25.6KB -> 6 blocks/CU (was grid-limited at 4). Every wave's diagonal is the block's
// last tile -> no idle wave slots. Per-CU resident set (bid = c+256j): i = 31-4j-((j+m0)&3)
// -> exactly 132 tile-units per CU, LPT order, bh fixed per CU (XCD-packed L2).
// Fixed-max softmax (raw v_exp_f32), lsum via ones-MFMA, swizzled K/Vt staging.
__global__ __launch_bounds__(256, 5) void attn_kernel(
    const u16* __restrict__ Q, const u16* __restrict__ Vt, u16* __restrict__ AO)
{
  constexpr int LDP = 72;
  __shared__ __align__(16) u16 Ks[4096];        // [key 64][dh 64] swizzled, 8KB
  __shared__ __align__(16) u16 Vs[4096];        // [d 64][key 64] swizzled, 8KB
  __shared__ __align__(16) u16 Ps[4][16 * LDP]; // per-wave P (16 rows), 9KB

  const int tid  = threadIdx.x;
  const int wave = tid >> 6, lane = tid & 63;
  const int quad = lane >> 4, l15 = lane & 15;
  const int x7   = l15 & 7;
  const int bid  = blockIdx.x;
  // bits 0-5: bh, XCD-packed (bid%8 -> XCD; each XCD owns 8 bh = 4MB K+V = its L2)
  const int bh = (bid & 7) * 8 + ((bid >> 3) & 7);
  const int m  = bid >> 6;                       // 0..31
  const int jk = m >> 2, m0 = m & 3;
  const int i  = 31 - 4 * jk - ((jk + m0) & 3);  // q-tile (64 rows), LPT + per-CU balanced
  const int b = bh >> 4, h = bh & 15;
  const u16* Qbh = Q  + (size_t)bh * (T_ * DH_);
  const u16* Vbh = Vt + (size_t)bh * (DH_ * T_);
  const int q0w = i * 64 + wave * 16;      // wave's first q-row (16 rows)
  const int nkb = i + 1;                   // k-tiles; last tile is every wave's diagonal
  u16* myP = &Ps[wave][0];

  const float C1 = 0.18033688f;    // log2(e)/sqrt(64)
  const float C2 = -28.8539008f;   // -20*log2(e)  (fixed max M=20, shift-invariant)
  const bf16x8 ones = { 0x3F80, 0x3F80, 0x3F80, 0x3F80, 0x3F80, 0x3F80, 0x3F80, 0x3F80 };

  // Q fragments (A-operand, m = l15 -> rows q0w..q0w+15), direct global, once
  bf16x8 qf[2];
#pragma unroll
  for (int ks = 0; ks < 2; ks++)
    qf[ks] = *(const bf16x8*)(Qbh + (size_t)(q0w + l15) * DH_ + ks * 32 + quad * 8);

  f32x4 o[4] = {};
  f32x4 lsumv = {};

  auto tilecomp = [&](int kb, auto DIAGC) {
    constexpr bool DIAG = decltype(DIAGC)::value;
    const int k0 = kb * 64;
    // S = Q K^T  (C rows = q0w + quad*4+r, cols = key = nt*16+l15)
    f32x4 s[4] = {};
#pragma unroll
    for (int ks = 0; ks < 2; ks++)
#pragma unroll
      for (int nt = 0; nt < 4; nt++) {
        bf16x8 kf = *(const bf16x8*)(&Ks[(nt * 16 + l15) * 64 + (((ks * 4 + quad) ^ x7) * 8)]);
        s[nt] = __builtin_amdgcn_mfma_f32_16x16x32_bf16(qf[ks], kf, s[nt], 0, 0, 0);
      }

    // fixed-max softmax: p = exp2(s*C1 + C2), raw v_exp_f32; store P (bf16)
#pragma unroll
    for (int nt = 0; nt < 4; nt++)
#pragma unroll
      for (int r = 0; r < 4; r++) {
        float p = __builtin_amdgcn_exp2f(s[nt][r] * C1 + C2);
        if constexpr (DIAG) {
          int qg = q0w + quad * 4 + r;
          int kg = k0 + nt * 16 + l15;
          p = (kg <= qg) ? p : 0.0f;
        }
        myP[(quad * 4 + r) * LDP + nt * 16 + l15] = f2b(p);
      }

    // O += P V; row-sums via ones-MFMA (rides the MFMA pipe)
#pragma unroll
    for (int ks2 = 0; ks2 < 2; ks2++) {
      bf16x8 pf = *(const bf16x8*)(&myP[l15 * LDP + ks2 * 32 + quad * 8]);
      lsumv = __builtin_amdgcn_mfma_f32_16x16x32_bf16(pf, ones, lsumv, 0, 0, 0);
#pragma unroll
      for (int dt = 0; dt < 4; dt++) {
        bf16x8 vf = *(const bf16x8*)(&Vs[(dt * 16 + l15) * 64 + (((ks2 * 4 + quad) ^ x7) * 8)]);
        o[dt] = __builtin_amdgcn_mfma_f32_16x16x32_bf16(pf, vf, o[dt], 0, 0, 0);
      }
    }
  };

  for (int kb = 0; kb < nkb; kb++) {
    const int k0 = kb * 64;
    // stage K-tile [key][dh] and Vt-tile [d][key]: 512 chunks each, 2/thread, swizzled
#pragma unroll
    for (int it = 0; it < 2; it++) {
      int ch  = it * 256 + tid;
      int row = ch >> 3;
      int cc  = (ch & 7) ^ (row & 7);
      GLDS16(Qbh + (size_t)(k0 + row) * DH_ + cc * 8, &Ks[(it * 256 + wave * 64) * 8]);
      GLDS16(Vbh + (size_t)row * T_ + k0 + cc * 8,    &Vs[(it * 256 + wave * 64) * 8]);
    }
    __syncthreads();

    if (kb < nkb - 1) tilecomp(kb, std::false_type{});
    else              tilecomp(kb, std::true_type{});
    __syncthreads();
  }

  // epilogue: lsumv holds full row sums (C-layout row = quad*4+r)
#pragma unroll
  for (int r = 0; r < 4; r++) {
    float rl = 1.0f / lsumv[r];
    int t = q0w + quad * 4 + r;
#pragma unroll
    for (int dt = 0; dt < 4; dt++)
      AO[((size_t)(b * T_ + t)) * C_ + h * DH_ + dt * 16 + l15] = f2b(o[dt][r] * rl);
  }
}

extern "C" void kernel_launch(void* const* d_in, const int* in_sizes, int n_in,
                              void* d_out, int out_size, void* d_ws, size_t ws_size,
                              hipStream_t stream) {
  (void)in_sizes; (void)n_in; (void)out_size; (void)ws_size;
  const float* x  = (const float*)d_in[0];
  const float* Wq = (const float*)d_in[1];
  // d_in[2] = W_k unused (reference bug: K uses W_q)
  const float* Wv = (const float*)d_in[3];
  const float* Wo = (const float*)d_in[4];

  // workspace (u16 elems); AO reuses Xb slot (dead after gemm1)
  u16* Xb  = (u16*)d_ws;            // 8388608 : x bf16; later AO [B,T,C]
  u16* AOw = Xb;
  u16* Wqb = Xb  + 8388608;         // 1048576
  u16* Wvb = Wqb + 1048576;         // 1048576 (adjacent -> fused N=2048 GEMM)
  u16* Wob = Wvb + 1048576;         // 1048576
  u16* Qw  = Wob + 1048576;         // 8388608 : Q [B,H,T,Dh]
  u16* Vtw = Qw  + 8388608;         // 8388608 : Vt [B,H,Dh,T] (gemm1 writes directly)
  // total 54,525,952 bytes

  cast_all_kernel<<<11264, 256, 0, stream>>>(x, Wq, Wv, Wo, Xb, Wqb, Wvb, Wob);

  // fused Q+V projection; V half written pre-transposed (Vt base = Qw + 8388608)
  gemm_bt_kernel<<<dim3(64, 16), 256, 0, stream>>>(Xb, Wqb, (void*)Qw, 0);

  attn_kernel<<<2048, 256, 0, stream>>>(Qw, Vtw, AOw);

  gemm_bt512_kernel<<<dim3(64, 8), 512, 0, stream>>>(AOw, Wob, (float*)d_out);
}

// Round 10
// 229.862 us; speedup vs baseline: 1.8754x; 1.2297x over previous
//
#include <hip/hip_runtime.h>
#include <hip/hip_bf16.h>
#include <type_traits>

typedef unsigned short u16;
typedef __attribute__((ext_vector_type(8))) short bf16x8;
typedef __attribute__((ext_vector_type(4))) float f32x4;

#define B_  4
#define T_  2048
#define C_  1024
#define H_  16
#define DH_ 64
#define M_  (B_*T_)   // 8192

// async global->LDS, 16B per lane; LDS dest = wave-uniform base + lane*16
#define GLDS16(g, l) __builtin_amdgcn_global_load_lds( \
    (const __attribute__((address_space(1))) void*)(g), \
    (__attribute__((address_space(3))) void*)(l), 16, 0, 0)

__device__ __forceinline__ u16 f2b(float f) {
  union { __hip_bfloat16 h; u16 u; } cv;
  cv.h = __float2bfloat16(f);
  return cv.u;
}

// ---------------- all fp32 -> bf16 casts in one launch ----------------
__global__ void cast_all_kernel(const float* __restrict__ x,  const float* __restrict__ w0,
                                const float* __restrict__ w1, const float* __restrict__ w2,
                                u16* __restrict__ xo, u16* __restrict__ o0,
                                u16* __restrict__ o1, u16* __restrict__ o2) {
  int bid = blockIdx.x;
  const float* src; u16* dst; int blk;
  if (bid < 8192) { src = x; dst = xo; blk = bid; }
  else {
    int k = bid - 8192, w = k >> 10;
    src = (w == 0) ? w0 : (w == 1) ? w1 : w2;
    dst = (w == 0) ? o0 : (w == 1) ? o1 : o2;
    blk = k & 1023;
  }
  int i = (blk * 256 + threadIdx.x) * 4;
  float4 v = *(const float4*)(src + i);
  unsigned lo = (unsigned)f2b(v.x) | ((unsigned)f2b(v.y) << 16);
  unsigned hi = (unsigned)f2b(v.z) | ((unsigned)f2b(v.w) << 16);
  uint2 p; p.x = lo; p.y = hi;
  *(uint2*)(dst + i) = p;
}

// ---------------- GEMM (4-wave): C[m,n] = sum_k A[m,k]*B[n,k], 128x128, BK=64 ----------------
__global__ __launch_bounds__(256) void gemm_bt_kernel(
    const u16* __restrict__ A, const u16* __restrict__ Bm,
    void* __restrict__ Cout, int mode)
{
  constexpr int K = 1024;
  __shared__ __align__(16) u16 As[128 * 64];
  __shared__ __align__(16) u16 Bs[128 * 64];

  const int tid  = threadIdx.x;
  const int wave = tid >> 6, lane = tid & 63;
  const int quad = lane >> 4, l15 = lane & 15;
  const int x7   = l15 & 7;
  const int wm = (wave >> 1) * 64, wn = (wave & 1) * 64;
  const int tm = blockIdx.x * 128, tn = blockIdx.y * 128;

  f32x4 acc[4][4] = {};

  for (int k0 = 0; k0 < K; k0 += 64) {
#pragma unroll
    for (int it = 0; it < 4; it++) {
      int ch  = it * 256 + tid;
      int row = ch >> 3;
      int cc  = (ch & 7) ^ (row & 7);
      GLDS16(A  + (size_t)(tm + row) * K + k0 + cc * 8, &As[(it * 256 + wave * 64) * 8]);
      GLDS16(Bm + (size_t)(tn + row) * K + k0 + cc * 8, &Bs[(it * 256 + wave * 64) * 8]);
    }
    __syncthreads();

#pragma unroll
    for (int ks = 0; ks < 2; ks++) {
      bf16x8 af[4], bfr[4];
#pragma unroll
      for (int t = 0; t < 4; t++) {
        int co = ((ks * 4 + quad) ^ x7) * 8;
        af[t]  = *(const bf16x8*)(&As[(wm + t * 16 + l15) * 64 + co]);
        bfr[t] = *(const bf16x8*)(&Bs[(wn + t * 16 + l15) * 64 + co]);
      }
#pragma unroll
      for (int mt = 0; mt < 4; mt++)
#pragma unroll
        for (int nt = 0; nt < 4; nt++)
          acc[mt][nt] = __builtin_amdgcn_mfma_f32_16x16x32_bf16(af[mt], bfr[nt], acc[mt][nt], 0, 0, 0);
    }
    __syncthreads();
  }

  if (mode == 0) {
    u16* out = (u16*)Cout;
    if (tn < 1024) {
#pragma unroll
      for (int mt = 0; mt < 4; mt++)
#pragma unroll
        for (int nt = 0; nt < 4; nt++)
#pragma unroll
          for (int r = 0; r < 4; r++) {
            int gm = tm + wm + mt * 16 + quad * 4 + r;
            int gn = tn + wn + nt * 16 + l15;
            int b = gm >> 11, t = gm & 2047;
            int h = gn >> 6, d = gn & 63;
            out[((size_t)((b * 16 + h) * 2048 + t) << 6) + d] = f2b(acc[mt][nt][r]);
          }
    } else {
      // V half -> Vt [B,H,Dh,T] (fused transpose)
#pragma unroll
      for (int mt = 0; mt < 4; mt++)
#pragma unroll
        for (int nt = 0; nt < 4; nt++) {
          int gm0 = tm + wm + mt * 16 + quad * 4;
          int gn  = tn - 1024 + wn + nt * 16 + l15;
          int b = gm0 >> 11, t0 = gm0 & 2047;
          int h = gn >> 6, d = gn & 63;
          alignas(8) u16 tmp[4];
#pragma unroll
          for (int r = 0; r < 4; r++) tmp[r] = f2b(acc[mt][nt][r]);
          *(ushort4*)(out + 8388608 + (((size_t)(b * 16 + h) * 64 + d) << 11) + t0)
              = *(const ushort4*)tmp;
        }
    }
  } else {
    float* out = (float*)Cout;
#pragma unroll
    for (int mt = 0; mt < 4; mt++)
#pragma unroll
      for (int nt = 0; nt < 4; nt++)
#pragma unroll
        for (int r = 0; r < 4; r++) {
          int gm = tm + wm + mt * 16 + quad * 4 + r;
          int gn = tn + wn + nt * 16 + l15;
          out[(size_t)gm * 1024 + gn] = acc[mt][nt][r];
        }
  }
}

// ---------------- GEMM (8-wave, fp32 out): 128x128 tile, 512 threads ----------------
__global__ __launch_bounds__(512, 4) void gemm_bt512_kernel(
    const u16* __restrict__ A, const u16* __restrict__ Bm, float* __restrict__ out)
{
  constexpr int K = 1024;
  __shared__ __align__(16) u16 As[128 * 64];
  __shared__ __align__(16) u16 Bs[128 * 64];

  const int tid  = threadIdx.x;
  const int wave = tid >> 6, lane = tid & 63;   // wave 0..7
  const int quad = lane >> 4, l15 = lane & 15;
  const int x7   = l15 & 7;
  const int wm = (wave >> 1) * 32, wn = (wave & 1) * 64;
  const int tm = blockIdx.x * 128, tn = blockIdx.y * 128;

  f32x4 acc[2][4] = {};

  for (int k0 = 0; k0 < K; k0 += 64) {
#pragma unroll
    for (int it = 0; it < 2; it++) {
      int ch  = it * 512 + tid;
      int row = ch >> 3;
      int cc  = (ch & 7) ^ (row & 7);
      GLDS16(A  + (size_t)(tm + row) * K + k0 + cc * 8, &As[(it * 512 + wave * 64) * 8]);
      GLDS16(Bm + (size_t)(tn + row) * K + k0 + cc * 8, &Bs[(it * 512 + wave * 64) * 8]);
    }
    __syncthreads();

#pragma unroll
    for (int ks = 0; ks < 2; ks++) {
      bf16x8 af[2], bfr[4];
      int co = ((ks * 4 + quad) ^ x7) * 8;
#pragma unroll
      for (int t = 0; t < 2; t++)
        af[t]  = *(const bf16x8*)(&As[(wm + t * 16 + l15) * 64 + co]);
#pragma unroll
      for (int t = 0; t < 4; t++)
        bfr[t] = *(const bf16x8*)(&Bs[(wn + t * 16 + l15) * 64 + co]);
#pragma unroll
      for (int mt = 0; mt < 2; mt++)
#pragma unroll
        for (int nt = 0; nt < 4; nt++)
          acc[mt][nt] = __builtin_amdgcn_mfma_f32_16x16x32_bf16(af[mt], bfr[nt], acc[mt][nt], 0, 0, 0);
    }
    __syncthreads();
  }

#pragma unroll
  for (int mt = 0; mt < 2; mt++)
#pragma unroll
    for (int nt = 0; nt < 4; nt++)
#pragma unroll
      for (int r = 0; r < 4; r++) {
        int gm = tm + wm + mt * 16 + quad * 4 + r;
        int gn = tn + wn + nt * 16 + l15;
        out[(size_t)gm * 1024 + gn] = acc[mt][nt][r];
      }
}

// ---------------- causal flash attention, K==Q (reference bug), bf16 MFMA ----------------
// R9 decomposition (2048 four-wave blocks, 64 q-rows/block, 16 rows/wave; shared diagonal
// tile; LDS 25.6KB -> 6 blocks/CU possible) with the R9 spill fixed: __launch_bounds__(256,4)
// (cap 128 regs, R7-proven). LPT per-CU-balanced q-tile map, XCD-packed bh, fixed-max
// softmax (raw v_exp_f32), lsum via ones-MFMA, XOR-swizzled K/Vt staging.
__global__ __launch_bounds__(256, 4) void attn_kernel(
    const u16* __restrict__ Q, const u16* __restrict__ Vt, u16* __restrict__ AO)
{
  constexpr int LDP = 72;
  __shared__ __align__(16) u16 Ks[4096];        // [key 64][dh 64] swizzled, 8KB
  __shared__ __align__(16) u16 Vs[4096];        // [d 64][key 64] swizzled, 8KB
  __shared__ __align__(16) u16 Ps[4][16 * LDP]; // per-wave P (16 rows), 9KB

  const int tid  = threadIdx.x;
  const int wave = tid >> 6, lane = tid & 63;
  const int quad = lane >> 4, l15 = lane & 15;
  const int x7   = l15 & 7;
  const int bid  = blockIdx.x;
  // bits 0-5: bh, XCD-packed (bid%8 -> XCD; each XCD owns 8 bh = 4MB K+V = its L2)
  const int bh = (bid & 7) * 8 + ((bid >> 3) & 7);
  const int m  = bid >> 6;                       // 0..31
  const int jk = m >> 2, m0 = m & 3;
  const int i  = 31 - 4 * jk - ((jk + m0) & 3);  // q-tile (64 rows), LPT + per-CU balanced
  const int b = bh >> 4, h = bh & 15;
  const u16* Qbh = Q  + (size_t)bh * (T_ * DH_);
  const u16* Vbh = Vt + (size_t)bh * (DH_ * T_);
  const int q0w = i * 64 + wave * 16;      // wave's first q-row (16 rows)
  const int nkb = i + 1;                   // k-tiles; last tile is every wave's diagonal
  u16* myP = &Ps[wave][0];

  const float C1 = 0.18033688f;    // log2(e)/sqrt(64)
  const float C2 = -28.8539008f;   // -20*log2(e)  (fixed max M=20, shift-invariant)
  const bf16x8 ones = { 0x3F80, 0x3F80, 0x3F80, 0x3F80, 0x3F80, 0x3F80, 0x3F80, 0x3F80 };

  // Q fragments (A-operand, m = l15 -> rows q0w..q0w+15), direct global, once
  bf16x8 qf[2];
#pragma unroll
  for (int ks = 0; ks < 2; ks++)
    qf[ks] = *(const bf16x8*)(Qbh + (size_t)(q0w + l15) * DH_ + ks * 32 + quad * 8);

  f32x4 o[4] = {};
  f32x4 lsumv = {};

  auto tilecomp = [&](int kb, auto DIAGC) {
    constexpr bool DIAG = decltype(DIAGC)::value;
    const int k0 = kb * 64;
    // S = Q K^T  (C rows = q0w + quad*4+r, cols = key = nt*16+l15)
    f32x4 s[4] = {};
#pragma unroll
    for (int ks = 0; ks < 2; ks++)
#pragma unroll
      for (int nt = 0; nt < 4; nt++) {
        bf16x8 kf = *(const bf16x8*)(&Ks[(nt * 16 + l15) * 64 + (((ks * 4 + quad) ^ x7) * 8)]);
        s[nt] = __builtin_amdgcn_mfma_f32_16x16x32_bf16(qf[ks], kf, s[nt], 0, 0, 0);
      }

    // fixed-max softmax: p = exp2(s*C1 + C2), raw v_exp_f32; store P (bf16)
#pragma unroll
    for (int nt = 0; nt < 4; nt++)
#pragma unroll
      for (int r = 0; r < 4; r++) {
        float p = __builtin_amdgcn_exp2f(s[nt][r] * C1 + C2);
        if constexpr (DIAG) {
          int qg = q0w + quad * 4 + r;
          int kg = k0 + nt * 16 + l15;
          p = (kg <= qg) ? p : 0.0f;
        }
        myP[(quad * 4 + r) * LDP + nt * 16 + l15] = f2b(p);
      }

    // O += P V; row-sums via ones-MFMA (rides the MFMA pipe)
#pragma unroll
    for (int ks2 = 0; ks2 < 2; ks2++) {
      bf16x8 pf = *(const bf16x8*)(&myP[l15 * LDP + ks2 * 32 + quad * 8]);
      lsumv = __builtin_amdgcn_mfma_f32_16x16x32_bf16(pf, ones, lsumv, 0, 0, 0);
#pragma unroll
      for (int dt = 0; dt < 4; dt++) {
        bf16x8 vf = *(const bf16x8*)(&Vs[(dt * 16 + l15) * 64 + (((ks2 * 4 + quad) ^ x7) * 8)]);
        o[dt] = __builtin_amdgcn_mfma_f32_16x16x32_bf16(pf, vf, o[dt], 0, 0, 0);
      }
    }
  };

  for (int kb = 0; kb < nkb; kb++) {
    const int k0 = kb * 64;
    // stage K-tile [key][dh] and Vt-tile [d][key]: 512 chunks each, 2/thread, swizzled
#pragma unroll
    for (int it = 0; it < 2; it++) {
      int ch  = it * 256 + tid;
      int row = ch >> 3;
      int cc  = (ch & 7) ^ (row & 7);
      GLDS16(Qbh + (size_t)(k0 + row) * DH_ + cc * 8, &Ks[(it * 256 + wave * 64) * 8]);
      GLDS16(Vbh + (size_t)row * T_ + k0 + cc * 8,    &Vs[(it * 256 + wave * 64) * 8]);
    }
    __syncthreads();

    if (kb < nkb - 1) tilecomp(kb, std::false_type{});
    else              tilecomp(kb, std::true_type{});
    __syncthreads();
  }

  // epilogue: lsumv holds full row sums (C-layout row = quad*4+r)
#pragma unroll
  for (int r = 0; r < 4; r++) {
    float rl = 1.0f / lsumv[r];
    int t = q0w + quad * 4 + r;
#pragma unroll
    for (int dt = 0; dt < 4; dt++)
      AO[((size_t)(b * T_ + t)) * C_ + h * DH_ + dt * 16 + l15] = f2b(o[dt][r] * rl);
  }
}

extern "C" void kernel_launch(void* const* d_in, const int* in_sizes, int n_in,
                              void* d_out, int out_size, void* d_ws, size_t ws_size,
                              hipStream_t stream) {
  (void)in_sizes; (void)n_in; (void)out_size; (void)ws_size;
  const float* x  = (const float*)d_in[0];
  const float* Wq = (const float*)d_in[1];
  // d_in[2] = W_k unused (reference bug: K uses W_q)
  const float* Wv = (const float*)d_in[3];
  const float* Wo = (const float*)d_in[4];

  // workspace (u16 elems); AO reuses Xb slot (dead after gemm1)
  u16* Xb  = (u16*)d_ws;            // 8388608 : x bf16; later AO [B,T,C]
  u16* AOw = Xb;
  u16* Wqb = Xb  + 8388608;         // 1048576
  u16* Wvb = Wqb + 1048576;         // 1048576 (adjacent -> fused N=2048 GEMM)
  u16* Wob = Wvb + 1048576;         // 1048576
  u16* Qw  = Wob + 1048576;         // 8388608 : Q [B,H,T,Dh]
  u16* Vtw = Qw  + 8388608;         // 8388608 : Vt [B,H,Dh,T] (gemm1 writes directly)
  // total 54,525,952 bytes

  cast_all_kernel<<<11264, 256, 0, stream>>>(x, Wq, Wv, Wo, Xb, Wqb, Wvb, Wob);

  // fused Q+V projection; V half written pre-transposed (Vt base = Qw + 8388608)
  gemm_bt_kernel<<<dim3(64, 16), 256, 0, stream>>>(Xb, Wqb, (void*)Qw, 0);

  attn_kernel<<<2048, 256, 0, stream>>>(Qw, Vtw, AOw);

  gemm_bt512_kernel<<<dim3(64, 8), 512, 0, stream>>>(AOw, Wob, (float*)d_out);
}